// Round 1
// 2301.461 us; speedup vs baseline: 1.1322x; 1.1322x over previous
//
#include <hip/hip_runtime.h>

#define NN 100000
#define EE 1600000
#define ENN (EE + NN)
#define DIN 256
#define DH 128
#define PH 512

static constexpr float BN_EPS_C = 1e-5f;

typedef __bf16 bf16_t;
typedef bf16_t bf16x8 __attribute__((ext_vector_type(8)));
typedef bf16_t bf16x4 __attribute__((ext_vector_type(4)));
typedef float floatx4 __attribute__((ext_vector_type(4)));

// ---------------- graph build ----------------

__global__ void init_deg_k(int* __restrict__ deg1, int* __restrict__ deg2) {
    int i = blockIdx.x * 256 + threadIdx.x;
    if (i < NN) { deg1[i] = 1; deg2[i] = 1; }
}

__global__ void count_deg_k(const int* __restrict__ dst, int* __restrict__ deg) {
    int e = blockIdx.x * 256 + threadIdx.x;
    if (e < EE) atomicAdd(&deg[dst[e]], 1);
}

__global__ void dinv_k(const int* __restrict__ deg, float* __restrict__ dinv) {
    int i = blockIdx.x * 256 + threadIdx.x;
    if (i < NN) dinv[i] = rsqrtf((float)deg[i]);
}

__global__ void scan1_k(const int* __restrict__ deg, int* __restrict__ bsum) {
    __shared__ int sh[256];
    int t = threadIdx.x;
    int base = blockIdx.x * 1024 + t * 4;
    int s = 0;
#pragma unroll
    for (int i = 0; i < 4; i++) { int idx = base + i; if (idx < NN) s += deg[idx]; }
    sh[t] = s; __syncthreads();
    for (int off = 128; off > 0; off >>= 1) { if (t < off) sh[t] += sh[t + off]; __syncthreads(); }
    if (t == 0) bsum[blockIdx.x] = sh[0];
}

__global__ void scan2_k(int* __restrict__ bsum, int nb) {
    __shared__ int sh[128];
    int t = threadIdx.x;
    int my = (t < nb) ? bsum[t] : 0;
    sh[t] = my; __syncthreads();
    for (int off = 1; off < 128; off <<= 1) {
        int v = (t >= off) ? sh[t - off] : 0;
        __syncthreads(); sh[t] += v; __syncthreads();
    }
    if (t < nb) bsum[t] = sh[t] - my;
}

__global__ void scan3_k(const int* __restrict__ deg, const int* __restrict__ bsum,
                        int* __restrict__ rowoff) {
    __shared__ int sh[256];
    int t = threadIdx.x;
    int base = blockIdx.x * 1024 + t * 4;
    int v[4]; int s = 0;
#pragma unroll
    for (int i = 0; i < 4; i++) { int idx = base + i; v[i] = (idx < NN) ? deg[idx] : 0; s += v[i]; }
    int my = s;
    sh[t] = s; __syncthreads();
    for (int off = 1; off < 256; off <<= 1) {
        int x = (t >= off) ? sh[t - off] : 0;
        __syncthreads(); sh[t] += x; __syncthreads();
    }
    int run = sh[t] - my + bsum[blockIdx.x];
#pragma unroll
    for (int i = 0; i < 4; i++) { int idx = base + i; if (idx < NN) rowoff[idx] = run; run += v[i]; }
    if (blockIdx.x == 0 && t == 0) rowoff[NN] = ENN;
}

__global__ void csr_init_k(const int* __restrict__ rowoff, const float* __restrict__ dinv,
                           int* __restrict__ cursor, int2* __restrict__ csre) {
    int i = blockIdx.x * 256 + threadIdx.x;
    if (i < NN) {
        int p = rowoff[i];
        float d = dinv[i];
        csre[p] = make_int2(i, __float_as_int(d * d));
        cursor[i] = p + 1;
    }
}

__global__ void csr_place_k(const int* __restrict__ src, const int* __restrict__ dst,
                            const float* __restrict__ dinv, int* __restrict__ cursor,
                            int2* __restrict__ csre) {
    int e = blockIdx.x * 256 + threadIdx.x;
    if (e < EE) {
        int s = src[e], d = dst[e];
        int p = atomicAdd(&cursor[d], 1);
        csre[p] = make_int2(s, __float_as_int(dinv[s] * dinv[d]));
    }
}

// ---------------- fused 256-ch gather (student||teacher), bf16 rows ----------------
// one wave per dst node; lane covers 4 channels (8 B bf16x4 load per edge)

__global__ __launch_bounds__(256) void gather256_k(
    const int* __restrict__ ro, const int2* __restrict__ csre,
    const bf16_t* __restrict__ h,
    const float* __restrict__ bs, const float* __restrict__ bt,
    float* __restrict__ out)
{
    int wv = threadIdx.x >> 6, lane = threadIdx.x & 63;
    int d = blockIdx.x * 4 + wv;
    if (d >= NN) return;
    int beg = ro[d], end = ro[d + 1];
    int c4 = lane * 4;
    float a0 = 0.f, a1 = 0.f, a2 = 0.f, a3 = 0.f;
    for (int e = beg; e < end; ++e) {
        int2 ew = csre[e];
        float w = __int_as_float(ew.y);
        uint2 pr = *(const uint2*)(h + (size_t)ew.x * 256 + c4);
        a0 += w * __uint_as_float(pr.x << 16);
        a1 += w * __uint_as_float(pr.x & 0xffff0000u);
        a2 += w * __uint_as_float(pr.y << 16);
        a3 += w * __uint_as_float(pr.y & 0xffff0000u);
    }
    float b0 = (c4 < 128) ? bs[c4]     : bt[c4 - 128];
    float b1 = (c4 < 128) ? bs[c4 + 1] : bt[c4 - 127];
    float b2 = (c4 < 128) ? bs[c4 + 2] : bt[c4 - 126];
    float b3 = (c4 < 128) ? bs[c4 + 3] : bt[c4 - 125];
    float4 r = make_float4(a0 + b0, a1 + b1, a2 + b2, a3 + b3);
    *(float4*)&out[(size_t)d * 256 + c4] = r;
}

// ---------------- batch norm (256-ch concatenated) ----------------
// 1024 blocks x 256 threads; wave wv covers rows r0+wv, r0+wv+4, ...; lane covers 4 ch
// (float4 load = one full 1KiB row per wave per iteration). LDS cross-wave reduce,
// then one atomicAdd per channel per block (1024 adds/address total).

#define GSTAT 1024
#define SROWS ((NN + GSTAT - 1) / GSTAT)

__global__ __launch_bounds__(256) void bn_stats_cat_k(const float* __restrict__ x,
                                                      float* __restrict__ stats) {
    __shared__ float sh[2][4][256];
    int t = threadIdx.x;
    int wv = t >> 6, lane = t & 63;
    int c4 = lane * 4;
    int rend = (blockIdx.x + 1) * SROWS; if (rend > NN) rend = NN;
    float4 s = make_float4(0.f, 0.f, 0.f, 0.f);
    float4 q = make_float4(0.f, 0.f, 0.f, 0.f);
    for (int r = blockIdx.x * SROWS + wv; r < rend; r += 4) {
        float4 v = *(const float4*)&x[(size_t)r * 256 + c4];
        s.x += v.x; s.y += v.y; s.z += v.z; s.w += v.w;
        q.x += v.x * v.x; q.y += v.y * v.y; q.z += v.z * v.z; q.w += v.w * v.w;
    }
    *(float4*)&sh[0][wv][c4] = s;
    *(float4*)&sh[1][wv][c4] = q;
    __syncthreads();
    if (t < 128) {
        int which = t >> 6;            // 0: sum, 1: sumsq
        int c = (t & 63) * 4;
        float4 a  = *(float4*)&sh[which][0][c];
        float4 b  = *(float4*)&sh[which][1][c];
        float4 cc = *(float4*)&sh[which][2][c];
        float4 d  = *(float4*)&sh[which][3][c];
        atomicAdd(&stats[which * 256 + c],     a.x + b.x + cc.x + d.x);
        atomicAdd(&stats[which * 256 + c + 1], a.y + b.y + cc.y + d.y);
        atomicAdd(&stats[which * 256 + c + 2], a.z + b.z + cc.z + d.z);
        atomicAdd(&stats[which * 256 + c + 3], a.w + b.w + cc.w + d.w);
    }
}

// normalize+prelu -> bf16 256-ch buffer (mid-layer); float4-vectorized
__global__ void bn_prelu_cat_k(const float* __restrict__ x, const float* __restrict__ stats,
                               const float* __restrict__ gs, const float* __restrict__ gt,
                               const float* __restrict__ bes, const float* __restrict__ bet,
                               const float* __restrict__ as_, const float* __restrict__ at_,
                               bf16_t* __restrict__ out) {
    size_t i4 = ((size_t)blockIdx.x * 256 + threadIdx.x) * 4;
    if (i4 < (size_t)NN * 256) {
        int c = (int)(i4 & 255);
        bool st = c < 128;
        int cb = st ? c : c - 128;
        const float* gp  = st ? gs  : gt;
        const float* bep = st ? bes : bet;
        float al = st ? as_[0] : at_[0];
        float4 v = *(const float4*)&x[i4];
        float vv[4] = {v.x, v.y, v.z, v.w};
        bf16x4 o;
#pragma unroll
        for (int j = 0; j < 4; j++) {
            float mu  = stats[c + j] * (1.0f / NN);
            float var = stats[256 + c + j] * (1.0f / NN) - mu * mu;
            float sc  = rsqrtf(var + BN_EPS_C) * gp[cb + j];
            float r   = (vv[j] - mu) * sc + bep[cb + j];
            r = r >= 0.f ? r : al * r;
            o[j] = (bf16_t)r;
        }
        *(bf16x4*)&out[i4] = o;
    }
}

// final layer: student half -> fp32 d_out + bf16 copy; teacher half -> bf16; vectorized
__global__ void bn_prelu_out_k(const float* __restrict__ x, const float* __restrict__ stats,
                               const float* __restrict__ gs, const float* __restrict__ gt,
                               const float* __restrict__ bes, const float* __restrict__ bet,
                               const float* __restrict__ as_, const float* __restrict__ at_,
                               float* __restrict__ outs, bf16_t* __restrict__ outsb,
                               bf16_t* __restrict__ outt) {
    size_t i4 = ((size_t)blockIdx.x * 256 + threadIdx.x) * 4;
    if (i4 >= (size_t)NN * 256) return;
    int c = (int)(i4 & 255);
    size_t r = i4 >> 8;
    bool st = c < 128;
    int cb = st ? c : c - 128;
    const float* gp  = st ? gs  : gt;
    const float* bep = st ? bes : bet;
    float al = st ? as_[0] : at_[0];
    float4 v = *(const float4*)&x[i4];
    float vv[4] = {v.x, v.y, v.z, v.w};
    float res[4];
    bf16x4 o;
#pragma unroll
    for (int j = 0; j < 4; j++) {
        float mu  = stats[c + j] * (1.0f / NN);
        float var = stats[256 + c + j] * (1.0f / NN) - mu * mu;
        float sc  = rsqrtf(var + BN_EPS_C) * gp[cb + j];
        float rr  = (vv[j] - mu) * sc + bep[cb + j];
        rr = rr >= 0.f ? rr : al * rr;
        res[j] = rr;
        o[j] = (bf16_t)rr;
    }
    if (st) {
        *(float4*)&outs[r * 128 + cb] = make_float4(res[0], res[1], res[2], res[3]);
        *(bf16x4*)&outsb[r * 128 + cb] = o;
    } else {
        *(bf16x4*)&outt[r * 128 + cb] = o;
    }
}

// ---------------- weight transpose + bf16: Wt[m][k] = W[k][m] ----------------

__global__ void wt_k(const float* __restrict__ W, bf16_t* __restrict__ Wt, int K, int M) {
    int i = blockIdx.x * 256 + threadIdx.x;
    if (i < K * M) {
        int k = i / M, m = i - k * M;
        Wt[(size_t)m * K + k] = (bf16_t)W[i];
    }
}

// ---------------- bf16 MFMA GEMM ----------------
// C[nrows, Mlogical] = A[nrows,K] @ Wt^T; A fp32 or bf16 (lda stride), C fp32 or bf16 (ldc stride)

#define LDT 40

template <int K, typename AT, typename OT, bool BIAS, bool PRELU>
__global__ __launch_bounds__(256) void mgemm_k(
    const AT* __restrict__ A, int lda, const bf16_t* __restrict__ Wt,
    OT* __restrict__ C, int ldc, int nrows,
    const float* __restrict__ bias, const float* __restrict__ prelu_a)
{
    __shared__ __align__(16) bf16_t sA[128 * LDT];
    __shared__ __align__(16) bf16_t sB[128 * LDT];
    const int tid = threadIdx.x;
    const int row0 = blockIdx.x * 128;
    const int col0 = blockIdx.y * 128;
    const int lane = tid & 63, quad = lane >> 4, l15 = lane & 15;
    const int wv = tid >> 6, wrow = wv >> 1, wcol = wv & 1;

    const int sr = tid >> 1;          // staging row 0..127
    const int sh = (tid & 1) * 16;    // staging k sub-offset (elements)

    floatx4 acc[4][4] = {};

    const int arow = row0 + sr;
    const bool arow_ok = arow < nrows;
    const AT*     ag = A  + (size_t)arow * lda + sh;
    const bf16_t* bg = Wt + (size_t)(col0 + sr) * K + sh;

    for (int k0 = 0; k0 < K; k0 += 32) {
        __syncthreads();
        if constexpr (sizeof(AT) == 4) {
            float4 f0, f1, f2, f3;
            if (arow_ok) {
                const float4* p4 = (const float4*)(ag + k0);
                f0 = p4[0]; f1 = p4[1]; f2 = p4[2]; f3 = p4[3];
            } else {
                f0 = f1 = f2 = f3 = make_float4(0.f, 0.f, 0.f, 0.f);
            }
            bf16x8 u0 = {(bf16_t)f0.x, (bf16_t)f0.y, (bf16_t)f0.z, (bf16_t)f0.w,
                         (bf16_t)f1.x, (bf16_t)f1.y, (bf16_t)f1.z, (bf16_t)f1.w};
            bf16x8 u1 = {(bf16_t)f2.x, (bf16_t)f2.y, (bf16_t)f2.z, (bf16_t)f2.w,
                         (bf16_t)f3.x, (bf16_t)f3.y, (bf16_t)f3.z, (bf16_t)f3.w};
            *(bf16x8*)&sA[sr * LDT + sh]     = u0;
            *(bf16x8*)&sA[sr * LDT + sh + 8] = u1;
        } else {
            int4 w0, w1;
            if (arow_ok) {
                const int4* p4 = (const int4*)(ag + k0);
                w0 = p4[0]; w1 = p4[1];
            } else {
                w0 = make_int4(0, 0, 0, 0); w1 = make_int4(0, 0, 0, 0);
            }
            *(int4*)&sA[sr * LDT + sh]     = w0;
            *(int4*)&sA[sr * LDT + sh + 8] = w1;
        }
        {
            const int4* wp = (const int4*)(bg + k0);
            int4 w0 = wp[0], w1 = wp[1];
            *(int4*)&sB[sr * LDT + sh]     = w0;
            *(int4*)&sB[sr * LDT + sh + 8] = w1;
        }
        __syncthreads();

        bf16x8 af[4], bf[4];
#pragma unroll
        for (int r = 0; r < 4; r++)
            af[r] = *(const bf16x8*)&sA[(wrow * 64 + r * 16 + l15) * LDT + quad * 8];
#pragma unroll
        for (int c = 0; c < 4; c++)
            bf[c] = *(const bf16x8*)&sB[(wcol * 64 + c * 16 + l15) * LDT + quad * 8];
#pragma unroll
        for (int r = 0; r < 4; r++)
#pragma unroll
            for (int c = 0; c < 4; c++)
                acc[r][c] = __builtin_amdgcn_mfma_f32_16x16x32_bf16(af[r], bf[c], acc[r][c], 0, 0, 0);
    }

    const float alpha = PRELU ? prelu_a[0] : 0.f;
#pragma unroll
    for (int r = 0; r < 4; r++) {
        const int rbase = wrow * 64 + r * 16 + quad * 4;
#pragma unroll
        for (int c = 0; c < 4; c++) {
            const int gcol = col0 + wcol * 64 + c * 16 + l15;
            const float bv = BIAS ? bias[gcol] : 0.f;
#pragma unroll
            for (int j = 0; j < 4; j++) {
                const int grow = row0 + rbase + j;
                if (grow < nrows) {
                    float v = acc[r][c][j] + bv;
                    if (PRELU) v = v >= 0.f ? v : alpha * v;
                    C[(size_t)grow * ldc + gcol] = (OT)v;
                }
            }
        }
    }
}

// ---------------- loss (all bf16 inputs) ----------------

__global__ void loss_partial_k(const bf16_t* __restrict__ v1p, const bf16_t* __restrict__ v2t,
                               const bf16_t* __restrict__ v2p, const bf16_t* __restrict__ v1t,
                               float* __restrict__ partials) {
    __shared__ float shw[4];
    int t = threadIdx.x;
    int lane = t & 63, wv = t >> 6;
    float wsum = 0.f;
    for (int it = 0; it < 8; ++it) {
        int r = blockIdx.x * 32 + wv * 8 + it;
        if (r < NN) {
            const bf16_t* A = v1p + (size_t)r * DH;
            const bf16_t* B = v2t + (size_t)r * DH;
            const bf16_t* Cc = v2p + (size_t)r * DH;
            const bf16_t* D = v1t + (size_t)r * DH;
            float a0 = (float)A[lane], a1 = (float)A[lane + 64];
            float b0 = (float)B[lane], b1 = (float)B[lane + 64];
            float c0 = (float)Cc[lane], c1 = (float)Cc[lane + 64];
            float d0 = (float)D[lane], d1 = (float)D[lane + 64];
            float dot1 = a0 * b0 + a1 * b1;
            float na = a0 * a0 + a1 * a1, nb = b0 * b0 + b1 * b1;
            float dot2 = c0 * d0 + c1 * d1;
            float nc = c0 * c0 + c1 * c1, nd = d0 * d0 + d1 * d1;
            for (int off = 32; off > 0; off >>= 1) {
                dot1 += __shfl_down(dot1, off);
                na   += __shfl_down(na, off);
                nb   += __shfl_down(nb, off);
                dot2 += __shfl_down(dot2, off);
                nc   += __shfl_down(nc, off);
                nd   += __shfl_down(nd, off);
            }
            if (lane == 0) {
                float den1 = fmaxf(sqrtf(na), 1e-12f) * fmaxf(sqrtf(nb), 1e-12f);
                float den2 = fmaxf(sqrtf(nc), 1e-12f) * fmaxf(sqrtf(nd), 1e-12f);
                wsum += 4.f - 2.f * dot1 / den1 - 2.f * dot2 / den2;
            }
        }
    }
    if (lane == 0) shw[wv] = wsum;
    __syncthreads();
    if (t == 0) partials[blockIdx.x] = shw[0] + shw[1] + shw[2] + shw[3];
}

__global__ void loss_final_k(const float* __restrict__ partials, int n, float* __restrict__ out) {
    __shared__ float sh[256];
    int t = threadIdx.x;
    float s = 0.f;
    for (int i = t; i < n; i += 256) s += partials[i];
    sh[t] = s; __syncthreads();
    for (int off = 128; off > 0; off >>= 1) { if (t < off) sh[t] += sh[t + off]; __syncthreads(); }
    if (t == 0) out[0] = sh[0] / (float)NN;
}

// ---------------- host ----------------

extern "C" void kernel_launch(void* const* d_in, const int* in_sizes, int n_in,
                              void* d_out, int out_size, void* d_ws, size_t ws_size,
                              hipStream_t stream) {
    const float* x1 = (const float*)d_in[0];
    const float* x2 = (const float*)d_in[1];
    const int* ei1 = (const int*)d_in[2];
    const int* ei2 = (const int*)d_in[3];
    const float* sp[10]; for (int i = 0; i < 10; i++) sp[i] = (const float*)d_in[4 + i];
    const float* tp[10]; for (int i = 0; i < 10; i++) tp[i] = (const float*)d_in[14 + i];
    const float* pW1 = (const float*)d_in[24];
    const float* pb1 = (const float*)d_in[25];
    const float* pa  = (const float*)d_in[26];
    const float* pW2 = (const float*)d_in[27];
    const float* pb2 = (const float*)d_in[28];

    float* out = (float*)d_out;
    float* v1s = out;
    float* v2s = out + (size_t)NN * DH;
    float* lossp = out + (size_t)2 * NN * DH;

    char* p = (char*)d_ws;
    auto alloc = [&](size_t bytes) { char* r = p; p += (bytes + 255) & ~(size_t)255; return r; };
    int*   deg1   = (int*)alloc(NN * 4);
    int*   deg2   = (int*)alloc(NN * 4);
    float* dinv1  = (float*)alloc(NN * 4);
    float* dinv2  = (float*)alloc(NN * 4);
    int*   ro1    = (int*)alloc((NN + 1) * 4);
    int*   ro2    = (int*)alloc((NN + 1) * 4);
    int*   cursor = (int*)alloc(NN * 4);
    int*   bsum   = (int*)alloc(128 * 4);
    int2*  csre1  = (int2*)alloc((size_t)ENN * 8);
    int2*  csre2  = (int2*)alloc((size_t)ENN * 8);
    bf16_t* hcat  = (bf16_t*)alloc((size_t)NN * 256 * 2);  // GEMM out / normalized h1 (reused)
    bf16_t* h2    = (bf16_t*)alloc((size_t)NN * 256 * 2);  // layer-2 GEMM out
    float*  agg   = (float*)alloc((size_t)NN * 256 * 4);   // gather out; later predictor hidden (bf16)
    bf16_t* v1sb  = (bf16_t*)alloc((size_t)NN * DH * 2);
    bf16_t* v2sb  = (bf16_t*)alloc((size_t)NN * DH * 2);
    bf16_t* v1t   = (bf16_t*)alloc((size_t)NN * DH * 2);
    bf16_t* v2t   = (bf16_t*)alloc((size_t)NN * DH * 2);
    bf16_t* v1p   = (bf16_t*)alloc((size_t)NN * DH * 2);
    bf16_t* v2p   = (bf16_t*)alloc((size_t)NN * DH * 2);
    float* stats  = (float*)alloc(4 * 512 * 4);
    float* partials = (float*)alloc(4096 * 4);
    bf16_t* W1cat = (bf16_t*)alloc((size_t)2 * DIN * DH * 2);  // s||t layer-1 Wt, 256 rows x DIN
    bf16_t* sW2t = (bf16_t*)alloc((size_t)DH * DH * 2);
    bf16_t* tW2t = (bf16_t*)alloc((size_t)DH * DH * 2);
    bf16_t* pW1t = (bf16_t*)alloc((size_t)DH * PH * 2);
    bf16_t* pW2t = (bf16_t*)alloc((size_t)PH * DH * 2);

    const int GN256 = (NN + 255) / 256;
    const int GE256 = (EE + 255) / 256;
    const int NB_SCAN = (NN + 1023) / 1024;
    const int GMM = (NN + 127) / 128;      // 782
    const int GG = (NN + 3) / 4;           // 25000
    const int GEL4 = (NN * 256 / 4 + 255) / 256;  // 25000 (float4-vectorized elementwise)

    hipMemsetAsync(stats, 0, 4 * 512 * 4, stream);

    wt_k<<<(DIN * DH + 255) / 256, 256, 0, stream>>>(sp[0], W1cat, DIN, DH);
    wt_k<<<(DIN * DH + 255) / 256, 256, 0, stream>>>(tp[0], W1cat + (size_t)DH * DIN, DIN, DH);
    wt_k<<<(DH * DH + 255) / 256, 256, 0, stream>>>(sp[5], sW2t, DH, DH);
    wt_k<<<(DH * DH + 255) / 256, 256, 0, stream>>>(tp[5], tW2t, DH, DH);
    wt_k<<<(DH * PH + 255) / 256, 256, 0, stream>>>(pW1, pW1t, DH, PH);
    wt_k<<<(PH * DH + 255) / 256, 256, 0, stream>>>(pW2, pW2t, PH, DH);

    init_deg_k<<<GN256, 256, 0, stream>>>(deg1, deg2);
    count_deg_k<<<GE256, 256, 0, stream>>>(ei1 + EE, deg1);
    count_deg_k<<<GE256, 256, 0, stream>>>(ei2 + EE, deg2);
    dinv_k<<<GN256, 256, 0, stream>>>(deg1, dinv1);
    dinv_k<<<GN256, 256, 0, stream>>>(deg2, dinv2);

    scan1_k<<<NB_SCAN, 256, 0, stream>>>(deg1, bsum);
    scan2_k<<<1, 128, 0, stream>>>(bsum, NB_SCAN);
    scan3_k<<<NB_SCAN, 256, 0, stream>>>(deg1, bsum, ro1);
    csr_init_k<<<GN256, 256, 0, stream>>>(ro1, dinv1, cursor, csre1);
    csr_place_k<<<GE256, 256, 0, stream>>>(ei1, ei1 + EE, dinv1, cursor, csre1);

    scan1_k<<<NB_SCAN, 256, 0, stream>>>(deg2, bsum);
    scan2_k<<<1, 128, 0, stream>>>(bsum, NB_SCAN);
    scan3_k<<<NB_SCAN, 256, 0, stream>>>(deg2, bsum, ro2);
    csr_init_k<<<GN256, 256, 0, stream>>>(ro2, dinv2, cursor, csre2);
    csr_place_k<<<GE256, 256, 0, stream>>>(ei2, ei2 + EE, dinv2, cursor, csre2);

    // fused s||t encoder per view
    auto encoder = [&](const float* x, const int* ro, const int2* csre,
                       float* vs_out, bf16_t* vsb, bf16_t* vt, int set) {
        // layer 1: single fused GEMM (student cols 0-127, teacher cols 128-255), reads x once
        mgemm_k<DIN, float, bf16_t, false, false><<<dim3(GMM, 2), 256, 0, stream>>>(
            x, DIN, W1cat, hcat, 256, NN, nullptr, nullptr);
        gather256_k<<<GG, 256, 0, stream>>>(ro, csre, hcat, sp[1], tp[1], agg);
        bn_stats_cat_k<<<GSTAT, 256, 0, stream>>>(agg, stats + set * 512);
        bn_prelu_cat_k<<<GEL4, 256, 0, stream>>>(agg, stats + set * 512,
            sp[2], tp[2], sp[3], tp[3], sp[4], tp[4], hcat);
        // layer 2
        mgemm_k<DH, bf16_t, bf16_t, false, false><<<dim3(GMM, 1), 256, 0, stream>>>(
            hcat, 256, sW2t, h2, 256, NN, nullptr, nullptr);
        mgemm_k<DH, bf16_t, bf16_t, false, false><<<dim3(GMM, 1), 256, 0, stream>>>(
            hcat + 128, 256, tW2t, h2 + 128, 256, NN, nullptr, nullptr);
        gather256_k<<<GG, 256, 0, stream>>>(ro, csre, h2, sp[6], tp[6], agg);
        bn_stats_cat_k<<<GSTAT, 256, 0, stream>>>(agg, stats + (set + 1) * 512);
        bn_prelu_out_k<<<GEL4, 256, 0, stream>>>(agg, stats + (set + 1) * 512,
            sp[7], tp[7], sp[8], tp[8], sp[9], tp[9], vs_out, vsb, vt);
    };

    encoder(x1, ro1, csre1, v1s, v1sb, v1t, 0);
    encoder(x2, ro2, csre2, v2s, v2sb, v2t, 2);

    // predictor (full N, hidden reuses agg as bf16 [N][512])
    bf16_t* hid = (bf16_t*)agg;
    auto predictor = [&](const bf16_t* vin, bf16_t* vout) {
        mgemm_k<DH, bf16_t, bf16_t, true, true><<<dim3(GMM, PH / 128), 256, 0, stream>>>(
            vin, DH, pW1t, hid, PH, NN, pb1, pa);
        mgemm_k<PH, bf16_t, bf16_t, true, false><<<dim3(GMM, 1), 256, 0, stream>>>(
            hid, PH, pW2t, vout, DH, NN, pb2, nullptr);
    };
    predictor(v1sb, v1p);
    predictor(v2sb, v2p);

    const int GL = (NN + 31) / 32;
    loss_partial_k<<<GL, 256, 0, stream>>>(v1p, v2t, v2p, v1t, partials);
    loss_final_k<<<1, 256, 0, stream>>>(partials, GL, lossp);
}

// Round 2
// 2087.888 us; speedup vs baseline: 1.2480x; 1.1023x over previous
//
#include <hip/hip_runtime.h>

#define NN 100000
#define EE 1600000
#define ENN (EE + NN)
#define DIN 256
#define DH 128
#define PH 512

static constexpr float BN_EPS_C = 1e-5f;

typedef __bf16 bf16_t;
typedef bf16_t bf16x8 __attribute__((ext_vector_type(8)));
typedef bf16_t bf16x4 __attribute__((ext_vector_type(4)));
typedef float floatx4 __attribute__((ext_vector_type(4)));

// ---------------- graph build ----------------

__global__ void init_deg_k(int* __restrict__ deg1, int* __restrict__ deg2) {
    int i = blockIdx.x * 256 + threadIdx.x;
    if (i < NN) { deg1[i] = 1; deg2[i] = 1; }
}

__global__ void count_deg_k(const int* __restrict__ dst, int* __restrict__ deg) {
    int e = blockIdx.x * 256 + threadIdx.x;
    if (e < EE) atomicAdd(&deg[dst[e]], 1);
}

__global__ void dinv_k(const int* __restrict__ deg, float* __restrict__ dinv) {
    int i = blockIdx.x * 256 + threadIdx.x;
    if (i < NN) dinv[i] = rsqrtf((float)deg[i]);
}

__global__ void scan1_k(const int* __restrict__ deg, int* __restrict__ bsum) {
    __shared__ int sh[256];
    int t = threadIdx.x;
    int base = blockIdx.x * 1024 + t * 4;
    int s = 0;
#pragma unroll
    for (int i = 0; i < 4; i++) { int idx = base + i; if (idx < NN) s += deg[idx]; }
    sh[t] = s; __syncthreads();
    for (int off = 128; off > 0; off >>= 1) { if (t < off) sh[t] += sh[t + off]; __syncthreads(); }
    if (t == 0) bsum[blockIdx.x] = sh[0];
}

__global__ void scan2_k(int* __restrict__ bsum, int nb) {
    __shared__ int sh[128];
    int t = threadIdx.x;
    int my = (t < nb) ? bsum[t] : 0;
    sh[t] = my; __syncthreads();
    for (int off = 1; off < 128; off <<= 1) {
        int v = (t >= off) ? sh[t - off] : 0;
        __syncthreads(); sh[t] += v; __syncthreads();
    }
    if (t < nb) bsum[t] = sh[t] - my;
}

__global__ void scan3_k(const int* __restrict__ deg, const int* __restrict__ bsum,
                        int* __restrict__ rowoff) {
    __shared__ int sh[256];
    int t = threadIdx.x;
    int base = blockIdx.x * 1024 + t * 4;
    int v[4]; int s = 0;
#pragma unroll
    for (int i = 0; i < 4; i++) { int idx = base + i; v[i] = (idx < NN) ? deg[idx] : 0; s += v[i]; }
    int my = s;
    sh[t] = s; __syncthreads();
    for (int off = 1; off < 256; off <<= 1) {
        int x = (t >= off) ? sh[t - off] : 0;
        __syncthreads(); sh[t] += x; __syncthreads();
    }
    int run = sh[t] - my + bsum[blockIdx.x];
#pragma unroll
    for (int i = 0; i < 4; i++) { int idx = base + i; if (idx < NN) rowoff[idx] = run; run += v[i]; }
    if (blockIdx.x == 0 && t == 0) rowoff[NN] = ENN;
}

__global__ void csr_init_k(const int* __restrict__ rowoff, const float* __restrict__ dinv,
                           int* __restrict__ cursor, int2* __restrict__ csre) {
    int i = blockIdx.x * 256 + threadIdx.x;
    if (i < NN) {
        int p = rowoff[i];
        float d = dinv[i];
        csre[p] = make_int2(i, __float_as_int(d * d));
        cursor[i] = p + 1;
    }
}

__global__ void csr_place_k(const int* __restrict__ src, const int* __restrict__ dst,
                            const float* __restrict__ dinv, int* __restrict__ cursor,
                            int2* __restrict__ csre) {
    int e = blockIdx.x * 256 + threadIdx.x;
    if (e < EE) {
        int s = src[e], d = dst[e];
        int p = atomicAdd(&cursor[d], 1);
        csre[p] = make_int2(s, __float_as_int(dinv[s] * dinv[d]));
    }
}

// ---------------- fused 256-ch gather (student||teacher), bf16 rows ----------------
// one wave per dst node; lane covers 4 channels (8 B bf16x4 load per edge).
// Edge loop unrolled 4-wide: 4 independent row loads in flight per wave (the serial
// csre->row dependent chain was the latency bottleneck: 33% HBM, 21% VALU, 0 MFMA).
// Tail: clamp edge index to end-1 (valid: self-loop guarantees deg>=1), zero the weight.

__global__ __launch_bounds__(256) void gather256_k(
    const int* __restrict__ ro, const int2* __restrict__ csre,
    const bf16_t* __restrict__ h,
    const float* __restrict__ bs, const float* __restrict__ bt,
    float* __restrict__ out)
{
    int wv = threadIdx.x >> 6, lane = threadIdx.x & 63;
    int d = blockIdx.x * 4 + wv;
    if (d >= NN) return;
    int beg = ro[d], end = ro[d + 1];
    int c4 = lane * 4;
    const bf16_t* hp = h + c4;
    float a0 = 0.f, a1 = 0.f, a2 = 0.f, a3 = 0.f;
    for (int e = beg; e < end; e += 4) {
        int e1 = (e + 1 < end) ? e + 1 : end - 1;
        int e2 = (e + 2 < end) ? e + 2 : end - 1;
        int e3 = (e + 3 < end) ? e + 3 : end - 1;
        int2 w0 = csre[e];
        int2 w1 = csre[e1];
        int2 w2 = csre[e2];
        int2 w3 = csre[e3];
        uint2 p0 = *(const uint2*)(hp + (size_t)w0.x * 256);
        uint2 p1 = *(const uint2*)(hp + (size_t)w1.x * 256);
        uint2 p2 = *(const uint2*)(hp + (size_t)w2.x * 256);
        uint2 p3 = *(const uint2*)(hp + (size_t)w3.x * 256);
        float f0 = __int_as_float(w0.y);
        float f1 = (e + 1 < end) ? __int_as_float(w1.y) : 0.f;
        float f2 = (e + 2 < end) ? __int_as_float(w2.y) : 0.f;
        float f3 = (e + 3 < end) ? __int_as_float(w3.y) : 0.f;
        a0 += f0 * __uint_as_float(p0.x << 16)
            + f1 * __uint_as_float(p1.x << 16)
            + f2 * __uint_as_float(p2.x << 16)
            + f3 * __uint_as_float(p3.x << 16);
        a1 += f0 * __uint_as_float(p0.x & 0xffff0000u)
            + f1 * __uint_as_float(p1.x & 0xffff0000u)
            + f2 * __uint_as_float(p2.x & 0xffff0000u)
            + f3 * __uint_as_float(p3.x & 0xffff0000u);
        a2 += f0 * __uint_as_float(p0.y << 16)
            + f1 * __uint_as_float(p1.y << 16)
            + f2 * __uint_as_float(p2.y << 16)
            + f3 * __uint_as_float(p3.y << 16);
        a3 += f0 * __uint_as_float(p0.y & 0xffff0000u)
            + f1 * __uint_as_float(p1.y & 0xffff0000u)
            + f2 * __uint_as_float(p2.y & 0xffff0000u)
            + f3 * __uint_as_float(p3.y & 0xffff0000u);
    }
    float b0 = (c4 < 128) ? bs[c4]     : bt[c4 - 128];
    float b1 = (c4 < 128) ? bs[c4 + 1] : bt[c4 - 127];
    float b2 = (c4 < 128) ? bs[c4 + 2] : bt[c4 - 126];
    float b3 = (c4 < 128) ? bs[c4 + 3] : bt[c4 - 125];
    float4 r = make_float4(a0 + b0, a1 + b1, a2 + b2, a3 + b3);
    *(float4*)&out[(size_t)d * 256 + c4] = r;
}

// ---------------- batch norm (256-ch concatenated) ----------------
// 1024 blocks x 256 threads; wave wv covers rows r0+wv, r0+wv+4, ...; lane covers 4 ch
// (float4 load = one full 1KiB row per wave per iteration). LDS cross-wave reduce,
// then one atomicAdd per channel per block (1024 adds/address total).

#define GSTAT 1024
#define SROWS ((NN + GSTAT - 1) / GSTAT)

__global__ __launch_bounds__(256) void bn_stats_cat_k(const float* __restrict__ x,
                                                      float* __restrict__ stats) {
    __shared__ float sh[2][4][256];
    int t = threadIdx.x;
    int wv = t >> 6, lane = t & 63;
    int c4 = lane * 4;
    int rend = (blockIdx.x + 1) * SROWS; if (rend > NN) rend = NN;
    float4 s = make_float4(0.f, 0.f, 0.f, 0.f);
    float4 q = make_float4(0.f, 0.f, 0.f, 0.f);
    for (int r = blockIdx.x * SROWS + wv; r < rend; r += 4) {
        float4 v = *(const float4*)&x[(size_t)r * 256 + c4];
        s.x += v.x; s.y += v.y; s.z += v.z; s.w += v.w;
        q.x += v.x * v.x; q.y += v.y * v.y; q.z += v.z * v.z; q.w += v.w * v.w;
    }
    *(float4*)&sh[0][wv][c4] = s;
    *(float4*)&sh[1][wv][c4] = q;
    __syncthreads();
    if (t < 128) {
        int which = t >> 6;            // 0: sum, 1: sumsq
        int c = (t & 63) * 4;
        float4 a  = *(float4*)&sh[which][0][c];
        float4 b  = *(float4*)&sh[which][1][c];
        float4 cc = *(float4*)&sh[which][2][c];
        float4 d  = *(float4*)&sh[which][3][c];
        atomicAdd(&stats[which * 256 + c],     a.x + b.x + cc.x + d.x);
        atomicAdd(&stats[which * 256 + c + 1], a.y + b.y + cc.y + d.y);
        atomicAdd(&stats[which * 256 + c + 2], a.z + b.z + cc.z + d.z);
        atomicAdd(&stats[which * 256 + c + 3], a.w + b.w + cc.w + d.w);
    }
}

// normalize+prelu -> bf16 256-ch buffer (mid-layer); float4-vectorized
__global__ void bn_prelu_cat_k(const float* __restrict__ x, const float* __restrict__ stats,
                               const float* __restrict__ gs, const float* __restrict__ gt,
                               const float* __restrict__ bes, const float* __restrict__ bet,
                               const float* __restrict__ as_, const float* __restrict__ at_,
                               bf16_t* __restrict__ out) {
    size_t i4 = ((size_t)blockIdx.x * 256 + threadIdx.x) * 4;
    if (i4 < (size_t)NN * 256) {
        int c = (int)(i4 & 255);
        bool st = c < 128;
        int cb = st ? c : c - 128;
        const float* gp  = st ? gs  : gt;
        const float* bep = st ? bes : bet;
        float al = st ? as_[0] : at_[0];
        float4 v = *(const float4*)&x[i4];
        float vv[4] = {v.x, v.y, v.z, v.w};
        bf16x4 o;
#pragma unroll
        for (int j = 0; j < 4; j++) {
            float mu  = stats[c + j] * (1.0f / NN);
            float var = stats[256 + c + j] * (1.0f / NN) - mu * mu;
            float sc  = rsqrtf(var + BN_EPS_C) * gp[cb + j];
            float r   = (vv[j] - mu) * sc + bep[cb + j];
            r = r >= 0.f ? r : al * r;
            o[j] = (bf16_t)r;
        }
        *(bf16x4*)&out[i4] = o;
    }
}

// final layer: student half -> fp32 d_out + bf16 copy; teacher half -> bf16; vectorized
__global__ void bn_prelu_out_k(const float* __restrict__ x, const float* __restrict__ stats,
                               const float* __restrict__ gs, const float* __restrict__ gt,
                               const float* __restrict__ bes, const float* __restrict__ bet,
                               const float* __restrict__ as_, const float* __restrict__ at_,
                               float* __restrict__ outs, bf16_t* __restrict__ outsb,
                               bf16_t* __restrict__ outt) {
    size_t i4 = ((size_t)blockIdx.x * 256 + threadIdx.x) * 4;
    if (i4 >= (size_t)NN * 256) return;
    int c = (int)(i4 & 255);
    size_t r = i4 >> 8;
    bool st = c < 128;
    int cb = st ? c : c - 128;
    const float* gp  = st ? gs  : gt;
    const float* bep = st ? bes : bet;
    float al = st ? as_[0] : at_[0];
    float4 v = *(const float4*)&x[i4];
    float vv[4] = {v.x, v.y, v.z, v.w};
    float res[4];
    bf16x4 o;
#pragma unroll
    for (int j = 0; j < 4; j++) {
        float mu  = stats[c + j] * (1.0f / NN);
        float var = stats[256 + c + j] * (1.0f / NN) - mu * mu;
        float sc  = rsqrtf(var + BN_EPS_C) * gp[cb + j];
        float rr  = (vv[j] - mu) * sc + bep[cb + j];
        rr = rr >= 0.f ? rr : al * rr;
        res[j] = rr;
        o[j] = (bf16_t)rr;
    }
    if (st) {
        *(float4*)&outs[r * 128 + cb] = make_float4(res[0], res[1], res[2], res[3]);
        *(bf16x4*)&outsb[r * 128 + cb] = o;
    } else {
        *(bf16x4*)&outt[r * 128 + cb] = o;
    }
}

// ---------------- weight transpose + bf16: Wt[m][k] = W[k][m] ----------------

__global__ void wt_k(const float* __restrict__ W, bf16_t* __restrict__ Wt, int K, int M) {
    int i = blockIdx.x * 256 + threadIdx.x;
    if (i < K * M) {
        int k = i / M, m = i - k * M;
        Wt[(size_t)m * K + k] = (bf16_t)W[i];
    }
}

// ---------------- bf16 MFMA GEMM ----------------
// C[nrows, Mlogical] = A[nrows,K] @ Wt^T; A fp32 or bf16 (lda stride), C fp32 or bf16 (ldc stride)

#define LDT 40

template <int K, typename AT, typename OT, bool BIAS, bool PRELU>
__global__ __launch_bounds__(256) void mgemm_k(
    const AT* __restrict__ A, int lda, const bf16_t* __restrict__ Wt,
    OT* __restrict__ C, int ldc, int nrows,
    const float* __restrict__ bias, const float* __restrict__ prelu_a)
{
    __shared__ __align__(16) bf16_t sA[128 * LDT];
    __shared__ __align__(16) bf16_t sB[128 * LDT];
    const int tid = threadIdx.x;
    const int row0 = blockIdx.x * 128;
    const int col0 = blockIdx.y * 128;
    const int lane = tid & 63, quad = lane >> 4, l15 = lane & 15;
    const int wv = tid >> 6, wrow = wv >> 1, wcol = wv & 1;

    const int sr = tid >> 1;          // staging row 0..127
    const int sh = (tid & 1) * 16;    // staging k sub-offset (elements)

    floatx4 acc[4][4] = {};

    const int arow = row0 + sr;
    const bool arow_ok = arow < nrows;
    const AT*     ag = A  + (size_t)arow * lda + sh;
    const bf16_t* bg = Wt + (size_t)(col0 + sr) * K + sh;

    for (int k0 = 0; k0 < K; k0 += 32) {
        __syncthreads();
        if constexpr (sizeof(AT) == 4) {
            float4 f0, f1, f2, f3;
            if (arow_ok) {
                const float4* p4 = (const float4*)(ag + k0);
                f0 = p4[0]; f1 = p4[1]; f2 = p4[2]; f3 = p4[3];
            } else {
                f0 = f1 = f2 = f3 = make_float4(0.f, 0.f, 0.f, 0.f);
            }
            bf16x8 u0 = {(bf16_t)f0.x, (bf16_t)f0.y, (bf16_t)f0.z, (bf16_t)f0.w,
                         (bf16_t)f1.x, (bf16_t)f1.y, (bf16_t)f1.z, (bf16_t)f1.w};
            bf16x8 u1 = {(bf16_t)f2.x, (bf16_t)f2.y, (bf16_t)f2.z, (bf16_t)f2.w,
                         (bf16_t)f3.x, (bf16_t)f3.y, (bf16_t)f3.z, (bf16_t)f3.w};
            *(bf16x8*)&sA[sr * LDT + sh]     = u0;
            *(bf16x8*)&sA[sr * LDT + sh + 8] = u1;
        } else {
            int4 w0, w1;
            if (arow_ok) {
                const int4* p4 = (const int4*)(ag + k0);
                w0 = p4[0]; w1 = p4[1];
            } else {
                w0 = make_int4(0, 0, 0, 0); w1 = make_int4(0, 0, 0, 0);
            }
            *(int4*)&sA[sr * LDT + sh]     = w0;
            *(int4*)&sA[sr * LDT + sh + 8] = w1;
        }
        {
            const int4* wp = (const int4*)(bg + k0);
            int4 w0 = wp[0], w1 = wp[1];
            *(int4*)&sB[sr * LDT + sh]     = w0;
            *(int4*)&sB[sr * LDT + sh + 8] = w1;
        }
        __syncthreads();

        bf16x8 af[4], bf[4];
#pragma unroll
        for (int r = 0; r < 4; r++)
            af[r] = *(const bf16x8*)&sA[(wrow * 64 + r * 16 + l15) * LDT + quad * 8];
#pragma unroll
        for (int c = 0; c < 4; c++)
            bf[c] = *(const bf16x8*)&sB[(wcol * 64 + c * 16 + l15) * LDT + quad * 8];
#pragma unroll
        for (int r = 0; r < 4; r++)
#pragma unroll
            for (int c = 0; c < 4; c++)
                acc[r][c] = __builtin_amdgcn_mfma_f32_16x16x32_bf16(af[r], bf[c], acc[r][c], 0, 0, 0);
    }

    const float alpha = PRELU ? prelu_a[0] : 0.f;
#pragma unroll
    for (int r = 0; r < 4; r++) {
        const int rbase = wrow * 64 + r * 16 + quad * 4;
#pragma unroll
        for (int c = 0; c < 4; c++) {
            const int gcol = col0 + wcol * 64 + c * 16 + l15;
            const float bv = BIAS ? bias[gcol] : 0.f;
#pragma unroll
            for (int j = 0; j < 4; j++) {
                const int grow = row0 + rbase + j;
                if (grow < nrows) {
                    float v = acc[r][c][j] + bv;
                    if (PRELU) v = v >= 0.f ? v : alpha * v;
                    C[(size_t)grow * ldc + gcol] = (OT)v;
                }
            }
        }
    }
}

// ---------------- loss (all bf16 inputs) ----------------

__global__ void loss_partial_k(const bf16_t* __restrict__ v1p, const bf16_t* __restrict__ v2t,
                               const bf16_t* __restrict__ v2p, const bf16_t* __restrict__ v1t,
                               float* __restrict__ partials) {
    __shared__ float shw[4];
    int t = threadIdx.x;
    int lane = t & 63, wv = t >> 6;
    float wsum = 0.f;
    for (int it = 0; it < 8; ++it) {
        int r = blockIdx.x * 32 + wv * 8 + it;
        if (r < NN) {
            const bf16_t* A = v1p + (size_t)r * DH;
            const bf16_t* B = v2t + (size_t)r * DH;
            const bf16_t* Cc = v2p + (size_t)r * DH;
            const bf16_t* D = v1t + (size_t)r * DH;
            float a0 = (float)A[lane], a1 = (float)A[lane + 64];
            float b0 = (float)B[lane], b1 = (float)B[lane + 64];
            float c0 = (float)Cc[lane], c1 = (float)Cc[lane + 64];
            float d0 = (float)D[lane], d1 = (float)D[lane + 64];
            float dot1 = a0 * b0 + a1 * b1;
            float na = a0 * a0 + a1 * a1, nb = b0 * b0 + b1 * b1;
            float dot2 = c0 * d0 + c1 * d1;
            float nc = c0 * c0 + c1 * c1, nd = d0 * d0 + d1 * d1;
            for (int off = 32; off > 0; off >>= 1) {
                dot1 += __shfl_down(dot1, off);
                na   += __shfl_down(na, off);
                nb   += __shfl_down(nb, off);
                dot2 += __shfl_down(dot2, off);
                nc   += __shfl_down(nc, off);
                nd   += __shfl_down(nd, off);
            }
            if (lane == 0) {
                float den1 = fmaxf(sqrtf(na), 1e-12f) * fmaxf(sqrtf(nb), 1e-12f);
                float den2 = fmaxf(sqrtf(nc), 1e-12f) * fmaxf(sqrtf(nd), 1e-12f);
                wsum += 4.f - 2.f * dot1 / den1 - 2.f * dot2 / den2;
            }
        }
    }
    if (lane == 0) shw[wv] = wsum;
    __syncthreads();
    if (t == 0) partials[blockIdx.x] = shw[0] + shw[1] + shw[2] + shw[3];
}

__global__ void loss_final_k(const float* __restrict__ partials, int n, float* __restrict__ out) {
    __shared__ float sh[256];
    int t = threadIdx.x;
    float s = 0.f;
    for (int i = t; i < n; i += 256) s += partials[i];
    sh[t] = s; __syncthreads();
    for (int off = 128; off > 0; off >>= 1) { if (t < off) sh[t] += sh[t + off]; __syncthreads(); }
    if (t == 0) out[0] = sh[0] / (float)NN;
}

// ---------------- host ----------------

extern "C" void kernel_launch(void* const* d_in, const int* in_sizes, int n_in,
                              void* d_out, int out_size, void* d_ws, size_t ws_size,
                              hipStream_t stream) {
    const float* x1 = (const float*)d_in[0];
    const float* x2 = (const float*)d_in[1];
    const int* ei1 = (const int*)d_in[2];
    const int* ei2 = (const int*)d_in[3];
    const float* sp[10]; for (int i = 0; i < 10; i++) sp[i] = (const float*)d_in[4 + i];
    const float* tp[10]; for (int i = 0; i < 10; i++) tp[i] = (const float*)d_in[14 + i];
    const float* pW1 = (const float*)d_in[24];
    const float* pb1 = (const float*)d_in[25];
    const float* pa  = (const float*)d_in[26];
    const float* pW2 = (const float*)d_in[27];
    const float* pb2 = (const float*)d_in[28];

    float* out = (float*)d_out;
    float* v1s = out;
    float* v2s = out + (size_t)NN * DH;
    float* lossp = out + (size_t)2 * NN * DH;

    char* p = (char*)d_ws;
    auto alloc = [&](size_t bytes) { char* r = p; p += (bytes + 255) & ~(size_t)255; return r; };
    int*   deg1   = (int*)alloc(NN * 4);
    int*   deg2   = (int*)alloc(NN * 4);
    float* dinv1  = (float*)alloc(NN * 4);
    float* dinv2  = (float*)alloc(NN * 4);
    int*   ro1    = (int*)alloc((NN + 1) * 4);
    int*   ro2    = (int*)alloc((NN + 1) * 4);
    int*   cursor = (int*)alloc(NN * 4);
    int*   bsum   = (int*)alloc(128 * 4);
    int2*  csre1  = (int2*)alloc((size_t)ENN * 8);
    int2*  csre2  = (int2*)alloc((size_t)ENN * 8);
    bf16_t* hcat  = (bf16_t*)alloc((size_t)NN * 256 * 2);  // GEMM out / normalized h1 (reused)
    bf16_t* h2    = (bf16_t*)alloc((size_t)NN * 256 * 2);  // layer-2 GEMM out
    float*  agg   = (float*)alloc((size_t)NN * 256 * 4);   // gather out; later predictor hidden (bf16)
    bf16_t* v1sb  = (bf16_t*)alloc((size_t)NN * DH * 2);
    bf16_t* v2sb  = (bf16_t*)alloc((size_t)NN * DH * 2);
    bf16_t* v1t   = (bf16_t*)alloc((size_t)NN * DH * 2);
    bf16_t* v2t   = (bf16_t*)alloc((size_t)NN * DH * 2);
    bf16_t* v1p   = (bf16_t*)alloc((size_t)NN * DH * 2);
    bf16_t* v2p   = (bf16_t*)alloc((size_t)NN * DH * 2);
    float* stats  = (float*)alloc(4 * 512 * 4);
    float* partials = (float*)alloc(4096 * 4);
    bf16_t* W1cat = (bf16_t*)alloc((size_t)2 * DIN * DH * 2);  // s||t layer-1 Wt, 256 rows x DIN
    bf16_t* sW2t = (bf16_t*)alloc((size_t)DH * DH * 2);
    bf16_t* tW2t = (bf16_t*)alloc((size_t)DH * DH * 2);
    bf16_t* pW1t = (bf16_t*)alloc((size_t)DH * PH * 2);
    bf16_t* pW2t = (bf16_t*)alloc((size_t)PH * DH * 2);

    const int GN256 = (NN + 255) / 256;
    const int GE256 = (EE + 255) / 256;
    const int NB_SCAN = (NN + 1023) / 1024;
    const int GMM = (NN + 127) / 128;      // 782
    const int GG = (NN + 3) / 4;           // 25000
    const int GEL4 = (NN * 256 / 4 + 255) / 256;  // 25000 (float4-vectorized elementwise)

    hipMemsetAsync(stats, 0, 4 * 512 * 4, stream);

    wt_k<<<(DIN * DH + 255) / 256, 256, 0, stream>>>(sp[0], W1cat, DIN, DH);
    wt_k<<<(DIN * DH + 255) / 256, 256, 0, stream>>>(tp[0], W1cat + (size_t)DH * DIN, DIN, DH);
    wt_k<<<(DH * DH + 255) / 256, 256, 0, stream>>>(sp[5], sW2t, DH, DH);
    wt_k<<<(DH * DH + 255) / 256, 256, 0, stream>>>(tp[5], tW2t, DH, DH);
    wt_k<<<(DH * PH + 255) / 256, 256, 0, stream>>>(pW1, pW1t, DH, PH);
    wt_k<<<(PH * DH + 255) / 256, 256, 0, stream>>>(pW2, pW2t, PH, DH);

    init_deg_k<<<GN256, 256, 0, stream>>>(deg1, deg2);
    count_deg_k<<<GE256, 256, 0, stream>>>(ei1 + EE, deg1);
    count_deg_k<<<GE256, 256, 0, stream>>>(ei2 + EE, deg2);
    dinv_k<<<GN256, 256, 0, stream>>>(deg1, dinv1);
    dinv_k<<<GN256, 256, 0, stream>>>(deg2, dinv2);

    scan1_k<<<NB_SCAN, 256, 0, stream>>>(deg1, bsum);
    scan2_k<<<1, 128, 0, stream>>>(bsum, NB_SCAN);
    scan3_k<<<NB_SCAN, 256, 0, stream>>>(deg1, bsum, ro1);
    csr_init_k<<<GN256, 256, 0, stream>>>(ro1, dinv1, cursor, csre1);
    csr_place_k<<<GE256, 256, 0, stream>>>(ei1, ei1 + EE, dinv1, cursor, csre1);

    scan1_k<<<NB_SCAN, 256, 0, stream>>>(deg2, bsum);
    scan2_k<<<1, 128, 0, stream>>>(bsum, NB_SCAN);
    scan3_k<<<NB_SCAN, 256, 0, stream>>>(deg2, bsum, ro2);
    csr_init_k<<<GN256, 256, 0, stream>>>(ro2, dinv2, cursor, csre2);
    csr_place_k<<<GE256, 256, 0, stream>>>(ei2, ei2 + EE, dinv2, cursor, csre2);

    // fused s||t encoder per view
    auto encoder = [&](const float* x, const int* ro, const int2* csre,
                       float* vs_out, bf16_t* vsb, bf16_t* vt, int set) {
        // layer 1: single fused GEMM (student cols 0-127, teacher cols 128-255), reads x once
        mgemm_k<DIN, float, bf16_t, false, false><<<dim3(GMM, 2), 256, 0, stream>>>(
            x, DIN, W1cat, hcat, 256, NN, nullptr, nullptr);
        gather256_k<<<GG, 256, 0, stream>>>(ro, csre, hcat, sp[1], tp[1], agg);
        bn_stats_cat_k<<<GSTAT, 256, 0, stream>>>(agg, stats + set * 512);
        bn_prelu_cat_k<<<GEL4, 256, 0, stream>>>(agg, stats + set * 512,
            sp[2], tp[2], sp[3], tp[3], sp[4], tp[4], hcat);
        // layer 2
        mgemm_k<DH, bf16_t, bf16_t, false, false><<<dim3(GMM, 1), 256, 0, stream>>>(
            hcat, 256, sW2t, h2, 256, NN, nullptr, nullptr);
        mgemm_k<DH, bf16_t, bf16_t, false, false><<<dim3(GMM, 1), 256, 0, stream>>>(
            hcat + 128, 256, tW2t, h2 + 128, 256, NN, nullptr, nullptr);
        gather256_k<<<GG, 256, 0, stream>>>(ro, csre, h2, sp[6], tp[6], agg);
        bn_stats_cat_k<<<GSTAT, 256, 0, stream>>>(agg, stats + (set + 1) * 512);
        bn_prelu_out_k<<<GEL4, 256, 0, stream>>>(agg, stats + (set + 1) * 512,
            sp[7], tp[7], sp[8], tp[8], sp[9], tp[9], vs_out, vsb, vt);
    };

    encoder(x1, ro1, csre1, v1s, v1sb, v1t, 0);
    encoder(x2, ro2, csre2, v2s, v2sb, v2t, 2);

    // predictor (full N, hidden reuses agg as bf16 [N][512])
    bf16_t* hid = (bf16_t*)agg;
    auto predictor = [&](const bf16_t* vin, bf16_t* vout) {
        mgemm_k<DH, bf16_t, bf16_t, true, true><<<dim3(GMM, PH / 128), 256, 0, stream>>>(
            vin, DH, pW1t, hid, PH, NN, pb1, pa);
        mgemm_k<PH, bf16_t, bf16_t, true, false><<<dim3(GMM, 1), 256, 0, stream>>>(
            hid, PH, pW2t, vout, DH, NN, pb2, nullptr);
    };
    predictor(v1sb, v1p);
    predictor(v2sb, v2p);

    const int GL = (NN + 31) / 32;
    loss_partial_k<<<GL, 256, 0, stream>>>(v1p, v2t, v2p, v1t, partials);
    loss_final_k<<<1, 256, 0, stream>>>(partials, GL, lossp);
}

// Round 4
// 2041.290 us; speedup vs baseline: 1.2765x; 1.0228x over previous
//
#include <hip/hip_runtime.h>

#define NN 100000
#define EE 1600000
#define ENN (EE + NN)
#define DIN 256
#define DH 128
#define PH 512

static constexpr float BN_EPS_C = 1e-5f;

typedef __bf16 bf16_t;
typedef bf16_t bf16x8 __attribute__((ext_vector_type(8)));
typedef bf16_t bf16x4 __attribute__((ext_vector_type(4)));
typedef float floatx4 __attribute__((ext_vector_type(4)));

// ---------------- graph build ----------------

__global__ void init_deg_k(int* __restrict__ deg1, int* __restrict__ deg2) {
    int i = blockIdx.x * 256 + threadIdx.x;
    if (i < NN) { deg1[i] = 1; deg2[i] = 1; }
}

__global__ void count_deg_k(const int* __restrict__ dst, int* __restrict__ deg) {
    int e = blockIdx.x * 256 + threadIdx.x;
    if (e < EE) atomicAdd(&deg[dst[e]], 1);
}

__global__ void dinv_k(const int* __restrict__ deg, float* __restrict__ dinv) {
    int i = blockIdx.x * 256 + threadIdx.x;
    if (i < NN) dinv[i] = rsqrtf((float)deg[i]);
}

__global__ void scan1_k(const int* __restrict__ deg, int* __restrict__ bsum) {
    __shared__ int sh[256];
    int t = threadIdx.x;
    int base = blockIdx.x * 1024 + t * 4;
    int s = 0;
#pragma unroll
    for (int i = 0; i < 4; i++) { int idx = base + i; if (idx < NN) s += deg[idx]; }
    sh[t] = s; __syncthreads();
    for (int off = 128; off > 0; off >>= 1) { if (t < off) sh[t] += sh[t + off]; __syncthreads(); }
    if (t == 0) bsum[blockIdx.x] = sh[0];
}

__global__ void scan2_k(int* __restrict__ bsum, int nb) {
    __shared__ int sh[128];
    int t = threadIdx.x;
    int my = (t < nb) ? bsum[t] : 0;
    sh[t] = my; __syncthreads();
    for (int off = 1; off < 128; off <<= 1) {
        int v = (t >= off) ? sh[t - off] : 0;
        __syncthreads(); sh[t] += v; __syncthreads();
    }
    if (t < nb) bsum[t] = sh[t] - my;
}

__global__ void scan3_k(const int* __restrict__ deg, const int* __restrict__ bsum,
                        int* __restrict__ rowoff) {
    __shared__ int sh[256];
    int t = threadIdx.x;
    int base = blockIdx.x * 1024 + t * 4;
    int v[4]; int s = 0;
#pragma unroll
    for (int i = 0; i < 4; i++) { int idx = base + i; v[i] = (idx < NN) ? deg[idx] : 0; s += v[i]; }
    int my = s;
    sh[t] = s; __syncthreads();
    for (int off = 1; off < 256; off <<= 1) {
        int x = (t >= off) ? sh[t - off] : 0;
        __syncthreads(); sh[t] += x; __syncthreads();
    }
    int run = sh[t] - my + bsum[blockIdx.x];
#pragma unroll
    for (int i = 0; i < 4; i++) { int idx = base + i; if (idx < NN) rowoff[idx] = run; run += v[i]; }
    if (blockIdx.x == 0 && t == 0) rowoff[NN] = ENN;
}

__global__ void csr_init_k(const int* __restrict__ rowoff, const float* __restrict__ dinv,
                           int* __restrict__ cursor, int2* __restrict__ csre) {
    int i = blockIdx.x * 256 + threadIdx.x;
    if (i < NN) {
        int p = rowoff[i];
        float d = dinv[i];
        csre[p] = make_int2(i, __float_as_int(d * d));
        cursor[i] = p + 1;
    }
}

__global__ void csr_place_k(const int* __restrict__ src, const int* __restrict__ dst,
                            const float* __restrict__ dinv, int* __restrict__ cursor,
                            int2* __restrict__ csre) {
    int e = blockIdx.x * 256 + threadIdx.x;
    if (e < EE) {
        int s = src[e], d = dst[e];
        int p = atomicAdd(&cursor[d], 1);
        csre[p] = make_int2(s, __float_as_int(dinv[s] * dinv[d]));
    }
}

// ---------------- fused 256-ch gather (student||teacher), bf16 rows ----------------
// one wave per dst node. Half-wave pairing: lanes 0-31 take even edges, 32-63 odd
// edges; each lane loads 16B (dwordx4 = 8 channels) so ONE VMEM instruction fetches
// TWO edge rows (1KB). 4 pair-slots unrolled -> 8 edges/iter, 4KB in flight/wave.
// Final __shfl_xor(.,32) merges the half-wave partials. Tail: clamp to end-1 (valid:
// self-loop guarantees deg>=1), zero the weight.

__global__ __launch_bounds__(256) void gather256_k(
    const int* __restrict__ ro, const int2* __restrict__ csre,
    const bf16_t* __restrict__ h,
    const float* __restrict__ bs, const float* __restrict__ bt,
    float* __restrict__ out)
{
    int wv = threadIdx.x >> 6, lane = threadIdx.x & 63;
    int d = blockIdx.x * 4 + wv;
    if (d >= NN) return;
    int beg = ro[d], end = ro[d + 1];
    int half = lane >> 5;            // 0: even edges, 1: odd edges
    int l32 = lane & 31;
    int c8 = l32 * 8;                // channel base of this lane's 16B slice
    const bf16_t* hp = h + c8;
    float acc[8] = {0.f, 0.f, 0.f, 0.f, 0.f, 0.f, 0.f, 0.f};

    for (int e = beg; e < end; e += 8) {       // wave-uniform loop
        int i0 = e + half;
        int i1 = i0 + 2, i2 = i0 + 4, i3 = i0 + 6;
        bool val0 = i0 < end, val1 = i1 < end, val2 = i2 < end, val3 = i3 < end;
        int j0 = val0 ? i0 : end - 1;
        int j1 = val1 ? i1 : end - 1;
        int j2 = val2 ? i2 : end - 1;
        int j3 = val3 ? i3 : end - 1;
        int2 w0 = csre[j0];
        int2 w1 = csre[j1];
        int2 w2 = csre[j2];
        int2 w3 = csre[j3];
        uint4 p0 = *(const uint4*)(hp + w0.x * 256);
        uint4 p1 = *(const uint4*)(hp + w1.x * 256);
        uint4 p2 = *(const uint4*)(hp + w2.x * 256);
        uint4 p3 = *(const uint4*)(hp + w3.x * 256);
        float f0 = val0 ? __int_as_float(w0.y) : 0.f;
        float f1 = val1 ? __int_as_float(w1.y) : 0.f;
        float f2 = val2 ? __int_as_float(w2.y) : 0.f;
        float f3 = val3 ? __int_as_float(w3.y) : 0.f;
#define GACC(P, F) \
        acc[0] += (F) * __uint_as_float((P).x << 16); \
        acc[1] += (F) * __uint_as_float((P).x & 0xffff0000u); \
        acc[2] += (F) * __uint_as_float((P).y << 16); \
        acc[3] += (F) * __uint_as_float((P).y & 0xffff0000u); \
        acc[4] += (F) * __uint_as_float((P).z << 16); \
        acc[5] += (F) * __uint_as_float((P).z & 0xffff0000u); \
        acc[6] += (F) * __uint_as_float((P).w << 16); \
        acc[7] += (F) * __uint_as_float((P).w & 0xffff0000u);
        GACC(p0, f0)
        GACC(p1, f1)
        GACC(p2, f2)
        GACC(p3, f3)
#undef GACC
    }

    // merge half-wave partials (lane l and l+32 hold the same 8 channels)
#pragma unroll
    for (int j = 0; j < 8; j++) acc[j] += __shfl_xor(acc[j], 32);

    // write: lane covers channels cB..cB+3; wave writes 1KB coalesced
    int cB = c8 + half * 4;
    int o = half * 4;
    float b0 = (cB < 128) ? bs[cB]     : bt[cB - 128];
    float b1 = (cB < 128) ? bs[cB + 1] : bt[cB - 127];
    float b2 = (cB < 128) ? bs[cB + 2] : bt[cB - 126];
    float b3 = (cB < 128) ? bs[cB + 3] : bt[cB - 125];
    float4 r = make_float4(acc[o] + b0, acc[o + 1] + b1, acc[o + 2] + b2, acc[o + 3] + b3);
    *(float4*)&out[(size_t)d * 256 + cB] = r;
}

// ---------------- batch norm (256-ch concatenated) ----------------

#define GSTAT 1024
#define SROWS ((NN + GSTAT - 1) / GSTAT)

__global__ __launch_bounds__(256) void bn_stats_cat_k(const float* __restrict__ x,
                                                      float* __restrict__ stats) {
    __shared__ float sh[2][4][256];
    int t = threadIdx.x;
    int wv = t >> 6, lane = t & 63;
    int c4 = lane * 4;
    int rend = (blockIdx.x + 1) * SROWS; if (rend > NN) rend = NN;
    float4 s = make_float4(0.f, 0.f, 0.f, 0.f);
    float4 q = make_float4(0.f, 0.f, 0.f, 0.f);
    for (int r = blockIdx.x * SROWS + wv; r < rend; r += 4) {
        float4 v = *(const float4*)&x[(size_t)r * 256 + c4];
        s.x += v.x; s.y += v.y; s.z += v.z; s.w += v.w;
        q.x += v.x * v.x; q.y += v.y * v.y; q.z += v.z * v.z; q.w += v.w * v.w;
    }
    *(float4*)&sh[0][wv][c4] = s;
    *(float4*)&sh[1][wv][c4] = q;
    __syncthreads();
    if (t < 128) {
        int which = t >> 6;            // 0: sum, 1: sumsq
        int c = (t & 63) * 4;
        float4 a  = *(float4*)&sh[which][0][c];
        float4 b  = *(float4*)&sh[which][1][c];
        float4 cc = *(float4*)&sh[which][2][c];
        float4 d  = *(float4*)&sh[which][3][c];
        atomicAdd(&stats[which * 256 + c],     a.x + b.x + cc.x + d.x);
        atomicAdd(&stats[which * 256 + c + 1], a.y + b.y + cc.y + d.y);
        atomicAdd(&stats[which * 256 + c + 2], a.z + b.z + cc.z + d.z);
        atomicAdd(&stats[which * 256 + c + 3], a.w + b.w + cc.w + d.w);
    }
}

// normalize+prelu -> bf16 256-ch buffer (mid-layer); float4-vectorized
__global__ void bn_prelu_cat_k(const float* __restrict__ x, const float* __restrict__ stats,
                               const float* __restrict__ gs, const float* __restrict__ gt,
                               const float* __restrict__ bes, const float* __restrict__ bet,
                               const float* __restrict__ as_, const float* __restrict__ at_,
                               bf16_t* __restrict__ out) {
    size_t i4 = ((size_t)blockIdx.x * 256 + threadIdx.x) * 4;
    if (i4 < (size_t)NN * 256) {
        int c = (int)(i4 & 255);
        bool st = c < 128;
        int cb = st ? c : c - 128;
        const float* gp  = st ? gs  : gt;
        const float* bep = st ? bes : bet;
        float al = st ? as_[0] : at_[0];
        float4 v = *(const float4*)&x[i4];
        float vv[4] = {v.x, v.y, v.z, v.w};
        bf16x4 o;
#pragma unroll
        for (int j = 0; j < 4; j++) {
            float mu  = stats[c + j] * (1.0f / NN);
            float var = stats[256 + c + j] * (1.0f / NN) - mu * mu;
            float sc  = rsqrtf(var + BN_EPS_C) * gp[cb + j];
            float r   = (vv[j] - mu) * sc + bep[cb + j];
            r = r >= 0.f ? r : al * r;
            o[j] = (bf16_t)r;
        }
        *(bf16x4*)&out[i4] = o;
    }
}

// final layer: student half -> fp32 d_out + bf16 copy; teacher half -> bf16; vectorized
__global__ void bn_prelu_out_k(const float* __restrict__ x, const float* __restrict__ stats,
                               const float* __restrict__ gs, const float* __restrict__ gt,
                               const float* __restrict__ bes, const float* __restrict__ bet,
                               const float* __restrict__ as_, const float* __restrict__ at_,
                               float* __restrict__ outs, bf16_t* __restrict__ outsb,
                               bf16_t* __restrict__ outt) {
    size_t i4 = ((size_t)blockIdx.x * 256 + threadIdx.x) * 4;
    if (i4 >= (size_t)NN * 256) return;
    int c = (int)(i4 & 255);
    size_t r = i4 >> 8;
    bool st = c < 128;
    int cb = st ? c : c - 128;
    const float* gp  = st ? gs  : gt;
    const float* bep = st ? bes : bet;
    float al = st ? as_[0] : at_[0];
    float4 v = *(const float4*)&x[i4];
    float vv[4] = {v.x, v.y, v.z, v.w};
    float res[4];
    bf16x4 o;
#pragma unroll
    for (int j = 0; j < 4; j++) {
        float mu  = stats[c + j] * (1.0f / NN);
        float var = stats[256 + c + j] * (1.0f / NN) - mu * mu;
        float sc  = rsqrtf(var + BN_EPS_C) * gp[cb + j];
        float rr  = (vv[j] - mu) * sc + bep[cb + j];
        rr = rr >= 0.f ? rr : al * rr;
        res[j] = rr;
        o[j] = (bf16_t)rr;
    }
    if (st) {
        *(float4*)&outs[r * 128 + cb] = make_float4(res[0], res[1], res[2], res[3]);
        *(bf16x4*)&outsb[r * 128 + cb] = o;
    } else {
        *(bf16x4*)&outt[r * 128 + cb] = o;
    }
}

// ---------------- weight transpose + bf16: Wt[m][k] = W[k][m] ----------------

__global__ void wt_k(const float* __restrict__ W, bf16_t* __restrict__ Wt, int K, int M) {
    int i = blockIdx.x * 256 + threadIdx.x;
    if (i < K * M) {
        int k = i / M, m = i - k * M;
        Wt[(size_t)m * K + k] = (bf16_t)W[i];
    }
}

// ---------------- bf16 MFMA GEMM ----------------
// C[nrows, Mlogical] = A[nrows,K] @ Wt^T; A fp32 or bf16 (lda stride), C fp32 or bf16 (ldc stride)
// aoffy: element offset added to A per blockIdx.y (lets one launch cover s/t halves
// of a concatenated input with per-y weight blocks via Wt row = col0+sr).

#define LDT 40

template <int K, typename AT, typename OT, bool BIAS, bool PRELU>
__global__ __launch_bounds__(256) void mgemm_k(
    const AT* __restrict__ A, int lda, const bf16_t* __restrict__ Wt,
    OT* __restrict__ C, int ldc, int nrows, int aoffy,
    const float* __restrict__ bias, const float* __restrict__ prelu_a)
{
    __shared__ __align__(16) bf16_t sA[128 * LDT];
    __shared__ __align__(16) bf16_t sB[128 * LDT];
    const int tid = threadIdx.x;
    const int row0 = blockIdx.x * 128;
    const int col0 = blockIdx.y * 128;
    const int lane = tid & 63, quad = lane >> 4, l15 = lane & 15;
    const int wv = tid >> 6, wrow = wv >> 1, wcol = wv & 1;

    const int sr = tid >> 1;          // staging row 0..127
    const int sh = (tid & 1) * 16;    // staging k sub-offset (elements)

    floatx4 acc[4][4] = {};

    const int arow = row0 + sr;
    const bool arow_ok = arow < nrows;
    const AT*     ag = A  + (size_t)arow * lda + sh + blockIdx.y * aoffy;
    const bf16_t* bg = Wt + (size_t)(col0 + sr) * K + sh;

    for (int k0 = 0; k0 < K; k0 += 32) {
        __syncthreads();
        if constexpr (sizeof(AT) == 4) {
            float4 f0, f1, f2, f3;
            if (arow_ok) {
                const float4* p4 = (const float4*)(ag + k0);
                f0 = p4[0]; f1 = p4[1]; f2 = p4[2]; f3 = p4[3];
            } else {
                f0 = f1 = f2 = f3 = make_float4(0.f, 0.f, 0.f, 0.f);
            }
            bf16x8 u0 = {(bf16_t)f0.x, (bf16_t)f0.y, (bf16_t)f0.z, (bf16_t)f0.w,
                         (bf16_t)f1.x, (bf16_t)f1.y, (bf16_t)f1.z, (bf16_t)f1.w};
            bf16x8 u1 = {(bf16_t)f2.x, (bf16_t)f2.y, (bf16_t)f2.z, (bf16_t)f2.w,
                         (bf16_t)f3.x, (bf16_t)f3.y, (bf16_t)f3.z, (bf16_t)f3.w};
            *(bf16x8*)&sA[sr * LDT + sh]     = u0;
            *(bf16x8*)&sA[sr * LDT + sh + 8] = u1;
        } else {
            int4 w0, w1;
            if (arow_ok) {
                const int4* p4 = (const int4*)(ag + k0);
                w0 = p4[0]; w1 = p4[1];
            } else {
                w0 = make_int4(0, 0, 0, 0); w1 = make_int4(0, 0, 0, 0);
            }
            *(int4*)&sA[sr * LDT + sh]     = w0;
            *(int4*)&sA[sr * LDT + sh + 8] = w1;
        }
        {
            const int4* wp = (const int4*)(bg + k0);
            int4 w0 = wp[0], w1 = wp[1];
            *(int4*)&sB[sr * LDT + sh]     = w0;
            *(int4*)&sB[sr * LDT + sh + 8] = w1;
        }
        __syncthreads();

        bf16x8 af[4], bf[4];
#pragma unroll
        for (int r = 0; r < 4; r++)
            af[r] = *(const bf16x8*)&sA[(wrow * 64 + r * 16 + l15) * LDT + quad * 8];
#pragma unroll
        for (int c = 0; c < 4; c++)
            bf[c] = *(const bf16x8*)&sB[(wcol * 64 + c * 16 + l15) * LDT + quad * 8];
#pragma unroll
        for (int r = 0; r < 4; r++)
#pragma unroll
            for (int c = 0; c < 4; c++)
                acc[r][c] = __builtin_amdgcn_mfma_f32_16x16x32_bf16(af[r], bf[c], acc[r][c], 0, 0, 0);
    }

    const float alpha = PRELU ? prelu_a[0] : 0.f;
#pragma unroll
    for (int r = 0; r < 4; r++) {
        const int rbase = wrow * 64 + r * 16 + quad * 4;
#pragma unroll
        for (int c = 0; c < 4; c++) {
            const int gcol = col0 + wcol * 64 + c * 16 + l15;
            const float bv = BIAS ? bias[gcol] : 0.f;
#pragma unroll
            for (int j = 0; j < 4; j++) {
                const int grow = row0 + rbase + j;
                if (grow < nrows) {
                    float v = acc[r][c][j] + bv;
                    if (PRELU) v = v >= 0.f ? v : alpha * v;
                    C[(size_t)grow * ldc + gcol] = (OT)v;
                }
            }
        }
    }
}

// ---------------- loss (all bf16 inputs) ----------------

__global__ void loss_partial_k(const bf16_t* __restrict__ v1p, const bf16_t* __restrict__ v2t,
                               const bf16_t* __restrict__ v2p, const bf16_t* __restrict__ v1t,
                               float* __restrict__ partials) {
    __shared__ float shw[4];
    int t = threadIdx.x;
    int lane = t & 63, wv = t >> 6;
    float wsum = 0.f;
    for (int it = 0; it < 8; ++it) {
        int r = blockIdx.x * 32 + wv * 8 + it;
        if (r < NN) {
            const bf16_t* A = v1p + (size_t)r * DH;
            const bf16_t* B = v2t + (size_t)r * DH;
            const bf16_t* Cc = v2p + (size_t)r * DH;
            const bf16_t* D = v1t + (size_t)r * DH;
            float a0 = (float)A[lane], a1 = (float)A[lane + 64];
            float b0 = (float)B[lane], b1 = (float)B[lane + 64];
            float c0 = (float)Cc[lane], c1 = (float)Cc[lane + 64];
            float d0 = (float)D[lane], d1 = (float)D[lane + 64];
            float dot1 = a0 * b0 + a1 * b1;
            float na = a0 * a0 + a1 * a1, nb = b0 * b0 + b1 * b1;
            float dot2 = c0 * d0 + c1 * d1;
            float nc = c0 * c0 + c1 * c1, nd = d0 * d0 + d1 * d1;
            for (int off = 32; off > 0; off >>= 1) {
                dot1 += __shfl_down(dot1, off);
                na   += __shfl_down(na, off);
                nb   += __shfl_down(nb, off);
                dot2 += __shfl_down(dot2, off);
                nc   += __shfl_down(nc, off);
                nd   += __shfl_down(nd, off);
            }
            if (lane == 0) {
                float den1 = fmaxf(sqrtf(na), 1e-12f) * fmaxf(sqrtf(nb), 1e-12f);
                float den2 = fmaxf(sqrtf(nc), 1e-12f) * fmaxf(sqrtf(nd), 1e-12f);
                wsum += 4.f - 2.f * dot1 / den1 - 2.f * dot2 / den2;
            }
        }
    }
    if (lane == 0) shw[wv] = wsum;
    __syncthreads();
    if (t == 0) partials[blockIdx.x] = shw[0] + shw[1] + shw[2] + shw[3];
}

__global__ void loss_final_k(const float* __restrict__ partials, int n, float* __restrict__ out) {
    __shared__ float sh[256];
    int t = threadIdx.x;
    float s = 0.f;
    for (int i = t; i < n; i += 256) s += partials[i];
    sh[t] = s; __syncthreads();
    for (int off = 128; off > 0; off >>= 1) { if (t < off) sh[t] += sh[t + off]; __syncthreads(); }
    if (t == 0) out[0] = sh[0] / (float)NN;
}

// ---------------- host ----------------

extern "C" void kernel_launch(void* const* d_in, const int* in_sizes, int n_in,
                              void* d_out, int out_size, void* d_ws, size_t ws_size,
                              hipStream_t stream) {
    const float* x1 = (const float*)d_in[0];
    const float* x2 = (const float*)d_in[1];
    const int* ei1 = (const int*)d_in[2];
    const int* ei2 = (const int*)d_in[3];
    const float* sp[10]; for (int i = 0; i < 10; i++) sp[i] = (const float*)d_in[4 + i];
    const float* tp[10]; for (int i = 0; i < 10; i++) tp[i] = (const float*)d_in[14 + i];
    const float* pW1 = (const float*)d_in[24];
    const float* pb1 = (const float*)d_in[25];
    const float* pa  = (const float*)d_in[26];
    const float* pW2 = (const float*)d_in[27];
    const float* pb2 = (const float*)d_in[28];

    float* out = (float*)d_out;
    float* v1s = out;
    float* v2s = out + (size_t)NN * DH;
    float* lossp = out + (size_t)2 * NN * DH;

    char* p = (char*)d_ws;
    auto alloc = [&](size_t bytes) { char* r = p; p += (bytes + 255) & ~(size_t)255; return r; };
    int*   deg1   = (int*)alloc(NN * 4);
    int*   deg2   = (int*)alloc(NN * 4);
    float* dinv1  = (float*)alloc(NN * 4);
    float* dinv2  = (float*)alloc(NN * 4);
    int*   ro1    = (int*)alloc((NN + 1) * 4);
    int*   ro2    = (int*)alloc((NN + 1) * 4);
    int*   cursor = (int*)alloc(NN * 4);
    int*   bsum   = (int*)alloc(128 * 4);
    int2*  csre1  = (int2*)alloc((size_t)ENN * 8);
    int2*  csre2  = (int2*)alloc((size_t)ENN * 8);
    bf16_t* hcat  = (bf16_t*)alloc((size_t)NN * 256 * 2);  // GEMM out / normalized h1 (reused)
    bf16_t* h2    = (bf16_t*)alloc((size_t)NN * 256 * 2);  // layer-2 GEMM out
    float*  agg   = (float*)alloc((size_t)NN * 256 * 4);   // gather out; later predictor hidden (bf16)
    bf16_t* v1sb  = (bf16_t*)alloc((size_t)NN * DH * 2);
    bf16_t* v2sb  = (bf16_t*)alloc((size_t)NN * DH * 2);
    bf16_t* v1t   = (bf16_t*)alloc((size_t)NN * DH * 2);
    bf16_t* v2t   = (bf16_t*)alloc((size_t)NN * DH * 2);
    bf16_t* v1p   = (bf16_t*)alloc((size_t)NN * DH * 2);
    bf16_t* v2p   = (bf16_t*)alloc((size_t)NN * DH * 2);
    float* stats  = (float*)alloc(4 * 512 * 4);
    float* partials = (float*)alloc(4096 * 4);
    bf16_t* W1cat = (bf16_t*)alloc((size_t)2 * DIN * DH * 2);  // s||t layer-1 Wt, 256 rows x DIN
    bf16_t* W2cat = (bf16_t*)alloc((size_t)2 * DH * DH * 2);   // s||t layer-2 Wt, 256 rows x DH
    bf16_t* pW1t = (bf16_t*)alloc((size_t)DH * PH * 2);
    bf16_t* pW2t = (bf16_t*)alloc((size_t)PH * DH * 2);

    const int GN256 = (NN + 255) / 256;
    const int GE256 = (EE + 255) / 256;
    const int NB_SCAN = (NN + 1023) / 1024;
    const int GMM = (NN + 127) / 128;      // 782
    const int GG = (NN + 3) / 4;           // 25000
    const int GEL4 = (NN * 256 / 4 + 255) / 256;  // 25000 (float4-vectorized elementwise)

    hipMemsetAsync(stats, 0, 4 * 512 * 4, stream);

    wt_k<<<(DIN * DH + 255) / 256, 256, 0, stream>>>(sp[0], W1cat, DIN, DH);
    wt_k<<<(DIN * DH + 255) / 256, 256, 0, stream>>>(tp[0], W1cat + (size_t)DH * DIN, DIN, DH);
    wt_k<<<(DH * DH + 255) / 256, 256, 0, stream>>>(sp[5], W2cat, DH, DH);
    wt_k<<<(DH * DH + 255) / 256, 256, 0, stream>>>(tp[5], W2cat + (size_t)DH * DH, DH, DH);
    wt_k<<<(DH * PH + 255) / 256, 256, 0, stream>>>(pW1, pW1t, DH, PH);
    wt_k<<<(PH * DH + 255) / 256, 256, 0, stream>>>(pW2, pW2t, PH, DH);

    init_deg_k<<<GN256, 256, 0, stream>>>(deg1, deg2);
    count_deg_k<<<GE256, 256, 0, stream>>>(ei1 + EE, deg1);
    count_deg_k<<<GE256, 256, 0, stream>>>(ei2 + EE, deg2);
    dinv_k<<<GN256, 256, 0, stream>>>(deg1, dinv1);
    dinv_k<<<GN256, 256, 0, stream>>>(deg2, dinv2);

    scan1_k<<<NB_SCAN, 256, 0, stream>>>(deg1, bsum);
    scan2_k<<<1, 128, 0, stream>>>(bsum, NB_SCAN);
    scan3_k<<<NB_SCAN, 256, 0, stream>>>(deg1, bsum, ro1);
    csr_init_k<<<GN256, 256, 0, stream>>>(ro1, dinv1, cursor, csre1);
    csr_place_k<<<GE256, 256, 0, stream>>>(ei1, ei1 + EE, dinv1, cursor, csre1);

    scan1_k<<<NB_SCAN, 256, 0, stream>>>(deg2, bsum);
    scan2_k<<<1, 128, 0, stream>>>(bsum, NB_SCAN);
    scan3_k<<<NB_SCAN, 256, 0, stream>>>(deg2, bsum, ro2);
    csr_init_k<<<GN256, 256, 0, stream>>>(ro2, dinv2, cursor, csre2);
    csr_place_k<<<GE256, 256, 0, stream>>>(ei2, ei2 + EE, dinv2, cursor, csre2);

    // fused s||t encoder per view
    auto encoder = [&](const float* x, const int* ro, const int2* csre,
                       float* vs_out, bf16_t* vsb, bf16_t* vt, int set) {
        // layer 1: single fused GEMM (student cols 0-127, teacher cols 128-255), reads x once
        mgemm_k<DIN, float, bf16_t, false, false><<<dim3(GMM, 2), 256, 0, stream>>>(
            x, DIN, W1cat, hcat, 256, NN, 0, nullptr, nullptr);
        gather256_k<<<GG, 256, 0, stream>>>(ro, csre, hcat, sp[1], tp[1], agg);
        bn_stats_cat_k<<<GSTAT, 256, 0, stream>>>(agg, stats + set * 512);
        bn_prelu_cat_k<<<GEL4, 256, 0, stream>>>(agg, stats + set * 512,
            sp[2], tp[2], sp[3], tp[3], sp[4], tp[4], hcat);
        // layer 2: single fused GEMM; blockIdx.y selects s/t half of A (aoffy=128)
        // and s/t weight block (W2cat row = col0+sr)
        mgemm_k<DH, bf16_t, bf16_t, false, false><<<dim3(GMM, 2), 256, 0, stream>>>(
            hcat, 256, W2cat, h2, 256, NN, 128, nullptr, nullptr);
        gather256_k<<<GG, 256, 0, stream>>>(ro, csre, h2, sp[6], tp[6], agg);
        bn_stats_cat_k<<<GSTAT, 256, 0, stream>>>(agg, stats + (set + 1) * 512);
        bn_prelu_out_k<<<GEL4, 256, 0, stream>>>(agg, stats + (set + 1) * 512,
            sp[7], tp[7], sp[8], tp[8], sp[9], tp[9], vs_out, vsb, vt);
    };

    encoder(x1, ro1, csre1, v1s, v1sb, v1t, 0);
    encoder(x2, ro2, csre2, v2s, v2sb, v2t, 2);

    // predictor (full N, hidden reuses agg as bf16 [N][512])
    bf16_t* hid = (bf16_t*)agg;
    auto predictor = [&](const bf16_t* vin, bf16_t* vout) {
        mgemm_k<DH, bf16_t, bf16_t, true, true><<<dim3(GMM, PH / 128), 256, 0, stream>>>(
            vin, DH, pW1t, hid, PH, NN, 0, pb1, pa);
        mgemm_k<PH, bf16_t, bf16_t, true, false><<<dim3(GMM, 1), 256, 0, stream>>>(
            hid, PH, pW2t, vout, DH, NN, 0, pb2, nullptr);
    };
    predictor(v1sb, v1p);
    predictor(v2sb, v2p);

    const int GL = (NN + 31) / 32;
    loss_partial_k<<<GL, 256, 0, stream>>>(v1p, v2t, v2p, v1t, partials);
    loss_final_k<<<1, 256, 0, stream>>>(partials, GL, lossp);
}